// Round 1
// baseline (282.589 us; speedup 1.0000x reference)
//
#include <hip/hip_runtime.h>
#include <math.h>

#define NG 16
#define DIM 64
#define LOG_2PI 1.8378770664093453f

// One wave (64 lanes) per batch row.
// Lane L: gaussian sub-index q = L>>4 (4 gaussians per wave-pass),
//         dim chunk      dpart = L&15 (4 dims each, float4).
// 4 passes over gaussian-blocks cover all 16 gaussians; each pass is one
// fully-coalesced 1 KiB float4 load from means and from covs.
__global__ __launch_bounds__(256) void gmm_loss_kernel(
    const float* __restrict__ means,
    const float* __restrict__ covs,
    const float* __restrict__ weights,
    const float* __restrict__ targets,
    float* __restrict__ out, int B)
{
    const int wave = threadIdx.x >> 6;
    const int lane = threadIdx.x & 63;
    const int b = blockIdx.x * 4 + wave;
    if (b >= B) return;

    const int q = lane >> 4;       // which gaussian within the 4-block
    const int dpart = lane & 15;   // which 4-dim chunk of the 64 dims

    // target chunk for this lane's dims (broadcast across the 4 groups; L1 serves it)
    const float4* t4 = (const float4*)(targets + (size_t)b * DIM);
    const float4 t = t4[dpart];

    const float4* m4 = (const float4*)(means + (size_t)b * (NG * DIM));
    const float4* v4 = (const float4*)(covs  + (size_t)b * (NG * DIM));

    float s[4];
#pragma unroll
    for (int kb = 0; kb < 4; ++kb) {
        const float4 m = m4[kb * 64 + lane];
        const float4 v = v4[kb * 64 + lane];
        float dx = t.x - m.x;
        float p = dx * dx * __builtin_amdgcn_rcpf(v.x) + __logf(v.x);
        dx = t.y - m.y;
        p += dx * dx * __builtin_amdgcn_rcpf(v.y) + __logf(v.y);
        dx = t.z - m.z;
        p += dx * dx * __builtin_amdgcn_rcpf(v.z) + __logf(v.z);
        dx = t.w - m.w;
        p += dx * dx * __builtin_amdgcn_rcpf(v.w) + __logf(v.w);
        // sum (quad + logdet) across the 16 lanes of this gaussian's group
        p += __shfl_xor(p, 1);
        p += __shfl_xor(p, 2);
        p += __shfl_xor(p, 4);
        p += __shfl_xor(p, 8);
        s[kb] = p;   // all 16 lanes of group q now hold gaussian (kb*4+q)'s sum
    }

    // log_prob -> clip -> + log(weight)
    float lpw[4];
#pragma unroll
    for (int kb = 0; kb < 4; ++kb) {
        float lp = -0.5f * (DIM * LOG_2PI + s[kb]);
        lp = fminf(fmaxf(lp, -100.0f), 0.0f);
        const float w = weights[(size_t)b * NG + kb * 4 + q];
        lpw[kb] = lp + __logf(w);
    }

    // logsumexp over 16 gaussians: 4 in-register + cross-group (xor 16, 32)
    float M = fmaxf(fmaxf(lpw[0], lpw[1]), fmaxf(lpw[2], lpw[3]));
    M = fmaxf(M, __shfl_xor(M, 16));
    M = fmaxf(M, __shfl_xor(M, 32));
    float sm = __expf(lpw[0] - M) + __expf(lpw[1] - M) +
               __expf(lpw[2] - M) + __expf(lpw[3] - M);
    sm += __shfl_xor(sm, 16);
    sm += __shfl_xor(sm, 32);

    if (lane == 0) {
        out[b] = -(M + __logf(sm));
    }
}

extern "C" void kernel_launch(void* const* d_in, const int* in_sizes, int n_in,
                              void* d_out, int out_size, void* d_ws, size_t ws_size,
                              hipStream_t stream) {
    const float* means   = (const float*)d_in[0];
    const float* covs    = (const float*)d_in[1];
    const float* weights = (const float*)d_in[2];
    const float* targets = (const float*)d_in[3];
    float* out = (float*)d_out;

    const int B = in_sizes[0] / (NG * DIM);   // 32768
    const int rows_per_block = 4;             // 4 waves x 64 lanes
    const int grid = (B + rows_per_block - 1) / rows_per_block;
    gmm_loss_kernel<<<grid, 256, 0, stream>>>(means, covs, weights, targets, out, B);
}

// Round 2
// 278.039 us; speedup vs baseline: 1.0164x; 1.0164x over previous
//
#include <hip/hip_runtime.h>
#include <math.h>

#define NG 16
#define DIM 64
#define LOG_2PI 1.8378770664093453f

// One wave (64 lanes) per batch row.
// Lane L: gaussian sub-index q = L>>4 (4 gaussians per wave-pass),
//         dim chunk      dpart = L&15 (4 dims each, float4).
// All 8 main loads (4 means + 4 covs float4s) are issued into explicit
// register arrays BEFORE any compute, so the wave keeps 8 vector loads in
// flight (the R1 version's 24-VGPR allocation serialized them -> 1.35 TB/s).
__global__ __launch_bounds__(256) void gmm_loss_kernel(
    const float* __restrict__ means,
    const float* __restrict__ covs,
    const float* __restrict__ weights,
    const float* __restrict__ targets,
    float* __restrict__ out, int B)
{
    const int wave = threadIdx.x >> 6;
    const int lane = threadIdx.x & 63;
    const int b = blockIdx.x * 4 + wave;
    if (b >= B) return;

    const int q = lane >> 4;       // which gaussian within the 4-block
    const int dpart = lane & 15;   // which 4-dim chunk of the 64 dims

    const float4* m4 = (const float4*)(means + (size_t)b * (NG * DIM));
    const float4* v4 = (const float4*)(covs  + (size_t)b * (NG * DIM));
    const float4* t4 = (const float4*)(targets + (size_t)b * DIM);

    // ---- issue ALL loads first (8x dwordx4 + target + weights in flight) ----
    float4 m[4], v[4];
#pragma unroll
    for (int kb = 0; kb < 4; ++kb) m[kb] = m4[kb * 64 + lane];
#pragma unroll
    for (int kb = 0; kb < 4; ++kb) v[kb] = v4[kb * 64 + lane];
    const float4 t = t4[dpart];
    float wgt[4];
#pragma unroll
    for (int kb = 0; kb < 4; ++kb) wgt[kb] = weights[(size_t)b * NG + kb * 4 + q];

    // ---- per-lane compute: quad-form partial + logdet via product ----
    float s[4];
#pragma unroll
    for (int kb = 0; kb < 4; ++kb) {
        float dx = t.x - m[kb].x;
        float p  = dx * dx * __builtin_amdgcn_rcpf(v[kb].x);
        dx = t.y - m[kb].y;
        p += dx * dx * __builtin_amdgcn_rcpf(v[kb].y);
        dx = t.z - m[kb].z;
        p += dx * dx * __builtin_amdgcn_rcpf(v[kb].z);
        dx = t.w - m[kb].w;
        p += dx * dx * __builtin_amdgcn_rcpf(v[kb].w);
        // log(v.x)+log(v.y)+log(v.z)+log(v.w) == log(product); product in [0.06,5.1]
        p += __logf(v[kb].x * v[kb].y * v[kb].z * v[kb].w);
        s[kb] = p;
    }

    // ---- reduce across the 16 lanes of each gaussian group; 4 independent
    //      chains interleaved per stage so DS latency overlaps ----
#pragma unroll
    for (int st = 1; st < 16; st <<= 1) {
#pragma unroll
        for (int kb = 0; kb < 4; ++kb) s[kb] += __shfl_xor(s[kb], st);
    }

    // log_prob -> clip -> + log(weight)
    float lpw[4];
#pragma unroll
    for (int kb = 0; kb < 4; ++kb) {
        float lp = -0.5f * (DIM * LOG_2PI + s[kb]);
        lp = fminf(fmaxf(lp, -100.0f), 0.0f);
        lpw[kb] = lp + __logf(wgt[kb]);
    }

    // logsumexp over 16 gaussians: 4 in-register + cross-group (xor 16, 32)
    float M = fmaxf(fmaxf(lpw[0], lpw[1]), fmaxf(lpw[2], lpw[3]));
    M = fmaxf(M, __shfl_xor(M, 16));
    M = fmaxf(M, __shfl_xor(M, 32));
    float sm = __expf(lpw[0] - M) + __expf(lpw[1] - M) +
               __expf(lpw[2] - M) + __expf(lpw[3] - M);
    sm += __shfl_xor(sm, 16);
    sm += __shfl_xor(sm, 32);

    if (lane == 0) {
        out[b] = -(M + __logf(sm));
    }
}

extern "C" void kernel_launch(void* const* d_in, const int* in_sizes, int n_in,
                              void* d_out, int out_size, void* d_ws, size_t ws_size,
                              hipStream_t stream) {
    const float* means   = (const float*)d_in[0];
    const float* covs    = (const float*)d_in[1];
    const float* weights = (const float*)d_in[2];
    const float* targets = (const float*)d_in[3];
    float* out = (float*)d_out;

    const int B = in_sizes[0] / (NG * DIM);   // 32768
    const int rows_per_block = 4;             // 4 waves x 64 lanes
    const int grid = (B + rows_per_block - 1) / rows_per_block;
    gmm_loss_kernel<<<grid, 256, 0, stream>>>(means, covs, weights, targets, out, B);
}

// Round 3
// 273.123 us; speedup vs baseline: 1.0347x; 1.0180x over previous
//
#include <hip/hip_runtime.h>
#include <math.h>

#define NG 16
#define DIM 64
#define LOG_2PI 1.8378770664093453f

// One 256-thread block per batch row.
// Row = 16 gaussians x 64 dims = 1024 floats = 256 float4s -> each lane loads
// EXACTLY one float4 of means + one of covs (independent, issued together).
// Gaussian g = tid>>4 (16 consecutive lanes per gaussian, within one wave).
// Reduce quad+logdet within the 16-lane group via 4 xor-shuffles, stash the
// 16 per-gaussian sums in LDS, then wave 0 alone does the 16-wide logsumexp
// while waves 1-3 retire (short per-wave serial tail = better latency hiding).
__global__ __launch_bounds__(256) void gmm_loss_kernel(
    const float* __restrict__ means,
    const float* __restrict__ covs,
    const float* __restrict__ weights,
    const float* __restrict__ targets,
    float* __restrict__ out)
{
    const int b = blockIdx.x;
    const int tid = threadIdx.x;
    const int lane = tid & 63;

    __shared__ float sbuf[NG];

    const float4* m4 = (const float4*)(means + (size_t)b * (NG * DIM));
    const float4* v4 = (const float4*)(covs  + (size_t)b * (NG * DIM));
    const float4* t4 = (const float4*)(targets + (size_t)b * DIM);

    // two independent 16B loads, back-to-back in flight; target chunk from L1
    const float4 m = m4[tid];
    const float4 v = v4[tid];
    const float4 t = t4[tid & 15];

    float dx = t.x - m.x;
    float p  = dx * dx * __builtin_amdgcn_rcpf(v.x);
    dx = t.y - m.y;
    p += dx * dx * __builtin_amdgcn_rcpf(v.y);
    dx = t.z - m.z;
    p += dx * dx * __builtin_amdgcn_rcpf(v.z);
    dx = t.w - m.w;
    p += dx * dx * __builtin_amdgcn_rcpf(v.w);
    // sum of 4 logs == log of product; product in [0.0625, 5.06] -> exact-safe
    p += __logf(v.x * v.y * v.z * v.w);

    // sum across the 16 lanes holding this gaussian's 64 dims
    p += __shfl_xor(p, 1);
    p += __shfl_xor(p, 2);
    p += __shfl_xor(p, 4);
    p += __shfl_xor(p, 8);

    if ((lane & 15) == 0) sbuf[tid >> 4] = p;
    __syncthreads();

    if (tid < 64) {
        const int g = lane & 15;          // lanes 16-63 duplicate group 0-15's work; harmless
        const float s = sbuf[g];
        float lp = -0.5f * (DIM * LOG_2PI + s);
        lp = fminf(fmaxf(lp, -100.0f), 0.0f);
        const float lw = lp + __logf(weights[(size_t)b * NG + g]);

        // 16-wide logsumexp within each 16-lane group (group 0 is the real one)
        float M = lw;
        M = fmaxf(M, __shfl_xor(M, 1));
        M = fmaxf(M, __shfl_xor(M, 2));
        M = fmaxf(M, __shfl_xor(M, 4));
        M = fmaxf(M, __shfl_xor(M, 8));
        float e = __expf(lw - M);
        e += __shfl_xor(e, 1);
        e += __shfl_xor(e, 2);
        e += __shfl_xor(e, 4);
        e += __shfl_xor(e, 8);

        if (tid == 0) out[b] = -(M + __logf(e));
    }
}

extern "C" void kernel_launch(void* const* d_in, const int* in_sizes, int n_in,
                              void* d_out, int out_size, void* d_ws, size_t ws_size,
                              hipStream_t stream) {
    const float* means   = (const float*)d_in[0];
    const float* covs    = (const float*)d_in[1];
    const float* weights = (const float*)d_in[2];
    const float* targets = (const float*)d_in[3];
    float* out = (float*)d_out;

    const int B = in_sizes[0] / (NG * DIM);   // 32768
    gmm_loss_kernel<<<B, 256, 0, stream>>>(means, covs, weights, targets, out);
}